// Round 1
// baseline (3155.210 us; speedup 1.0000x reference)
//
#include <hip/hip_runtime.h>

// ---------------------------------------------------------------------------
// DiscreteVAE forward, fp32 baseline.
// Sizes: B=8192 D=784 H=500 C=512 S=16 CS=8192 R=B*S=131072
// out = [recon (B*D) | obs (R*C) | latent (R*C)]
// ws  = [h1 (B*H) | h2 (B*H) | hdec (B*H) | T (S*C*H) | n2cb (C) | codes (R ints)]
// ---------------------------------------------------------------------------

#define TILE_M 128
#define TILE_N 128
#define TILE_K 16

// C = act(A @ B + bias), optional batch via blockIdx.z strides.
// Requires M % 128 == 0 (true for all uses: 8192, 512).
__global__ __launch_bounds__(256) void gemm_bias_act(
    const float* __restrict__ Ab, const float* __restrict__ Bb,
    const float* __restrict__ bias, float* __restrict__ Cb,
    int M, int N, int K, int do_relu,
    long long sA, long long sB, long long sC)
{
    const float* A = Ab + (long long)blockIdx.z * sA;
    const float* B = Bb + (long long)blockIdx.z * sB;
    float*       C = Cb + (long long)blockIdx.z * sC;

    __shared__ float As[TILE_K][TILE_M + 4];
    __shared__ float Bs[TILE_K][TILE_N + 4];

    const int tid = threadIdx.x;
    const int tx = tid & 15;         // 0..15 -> 8 cols each
    const int ty = tid >> 4;         // 0..15 -> 8 rows each
    const int row0 = blockIdx.y * TILE_M;
    const int col0 = blockIdx.x * TILE_N;

    const int a_row = tid >> 1;          // 0..127
    const int a_k8  = (tid & 1) * 8;     // 0 or 8
    const int b_k   = tid >> 4;          // 0..15
    const int b_c8  = (tid & 15) * 8;    // 0..120

    float acc[8][8];
    #pragma unroll
    for (int i = 0; i < 8; ++i)
        #pragma unroll
        for (int j = 0; j < 8; ++j) acc[i][j] = 0.f;

    for (int k0 = 0; k0 < K; k0 += TILE_K) {
        const bool kFull = (k0 + TILE_K <= K);
        // ---- A tile: 128 rows x 16 k, stored transposed As[k][m] ----
        if (kFull) {
            const float* src = A + (long long)(row0 + a_row) * K + (k0 + a_k8);
            float4 v0 = *(const float4*)(src);
            float4 v1 = *(const float4*)(src + 4);
            As[a_k8 + 0][a_row] = v0.x; As[a_k8 + 1][a_row] = v0.y;
            As[a_k8 + 2][a_row] = v0.z; As[a_k8 + 3][a_row] = v0.w;
            As[a_k8 + 4][a_row] = v1.x; As[a_k8 + 5][a_row] = v1.y;
            As[a_k8 + 6][a_row] = v1.z; As[a_k8 + 7][a_row] = v1.w;
        } else {
            #pragma unroll
            for (int i = 0; i < 8; ++i) {
                int k = k0 + a_k8 + i;
                As[a_k8 + i][a_row] =
                    (k < K) ? A[(long long)(row0 + a_row) * K + k] : 0.f;
            }
        }
        // ---- B tile: 16 k x 128 cols, stored Bs[k][n] ----
        if (kFull && (col0 + TILE_N <= N)) {
            const float* src = B + (long long)(k0 + b_k) * N + (col0 + b_c8);
            float4 v0 = *(const float4*)(src);
            float4 v1 = *(const float4*)(src + 4);
            Bs[b_k][b_c8 + 0] = v0.x; Bs[b_k][b_c8 + 1] = v0.y;
            Bs[b_k][b_c8 + 2] = v0.z; Bs[b_k][b_c8 + 3] = v0.w;
            Bs[b_k][b_c8 + 4] = v1.x; Bs[b_k][b_c8 + 5] = v1.y;
            Bs[b_k][b_c8 + 6] = v1.z; Bs[b_k][b_c8 + 7] = v1.w;
        } else {
            int k = k0 + b_k;
            #pragma unroll
            for (int i = 0; i < 8; ++i) {
                int c = col0 + b_c8 + i;
                Bs[b_k][b_c8 + i] =
                    (k < K && c < N) ? B[(long long)k * N + c] : 0.f;
            }
        }
        __syncthreads();
        #pragma unroll
        for (int kk = 0; kk < TILE_K; ++kk) {
            float ra[8], rb[8];
            #pragma unroll
            for (int i = 0; i < 8; ++i) ra[i] = As[kk][ty * 8 + i];
            #pragma unroll
            for (int j = 0; j < 8; ++j) rb[j] = Bs[kk][tx * 8 + j];
            #pragma unroll
            for (int i = 0; i < 8; ++i)
                #pragma unroll
                for (int j = 0; j < 8; ++j)
                    acc[i][j] = fmaf(ra[i], rb[j], acc[i][j]);
        }
        __syncthreads();
    }

    #pragma unroll
    for (int i = 0; i < 8; ++i) {
        int r = row0 + ty * 8 + i;
        #pragma unroll
        for (int j = 0; j < 8; ++j) {
            int c = col0 + tx * 8 + j;
            if (c < N) {
                float v = acc[i][j] + (bias ? bias[c] : 0.f);
                if (do_relu) v = fmaxf(v, 0.f);
                C[(long long)r * N + c] = v;
            }
        }
    }
}

// n2[j] = sum_k cb[j][k]^2  (one block of 64 per row)
__global__ __launch_bounds__(64) void row_norm2(
    const float* __restrict__ cb, float* __restrict__ n2)
{
    int j = blockIdx.x;
    int lane = threadIdx.x;
    float s = 0.f;
    for (int k = lane; k < 512; k += 64) {
        float v = cb[(long long)j * 512 + k];
        s += v * v;
    }
    #pragma unroll
    for (int off = 32; off > 0; off >>= 1) s += __shfl_down(s, off, 64);
    if (lane == 0) n2[j] = s;
}

// Fused distance-GEMM + per-row argmin over all 512 codes.
// 64 obs rows per block; d2 = (|o|^2 - 2 o.cb_j) + |cb_j|^2, np-argmin
// tie-break (first index wins: strict <, ascending j scan everywhere).
__global__ __launch_bounds__(256) void vq_argmin(
    const float* __restrict__ obs, const float* __restrict__ cb,
    const float* __restrict__ n2cb, int* __restrict__ codes)
{
    __shared__ float As[16][64 + 4];
    __shared__ float Bs[16][64 + 4];
    __shared__ float n2o[64];
    __shared__ float n2p[64][5];
    __shared__ float rv[64][17];
    __shared__ int   ri[64][17];
    __shared__ float bestv[64];
    __shared__ int   besti[64];

    const int tid = threadIdx.x;
    const int tx = tid & 15, ty = tid >> 4;
    const long long row0 = (long long)blockIdx.x * 64;

    {   // |obs_r|^2 for the 64 rows: 4 threads per row
        int r = tid >> 2, p = tid & 3;
        const float* orow = obs + (row0 + r) * 512 + p * 128;
        float s = 0.f;
        for (int k = 0; k < 128; k += 4) {
            float4 v = *(const float4*)(orow + k);
            s += v.x * v.x + v.y * v.y + v.z * v.z + v.w * v.w;
        }
        n2p[r][p] = s;
    }
    __syncthreads();
    if (tid < 64) {
        n2o[tid] = (n2p[tid][0] + n2p[tid][1]) + (n2p[tid][2] + n2p[tid][3]);
        bestv[tid] = 3.4e38f;
        besti[tid] = 0;
    }

    const int l_r  = tid >> 2;          // 0..63
    const int l_k4 = (tid & 3) * 4;     // 0,4,8,12

    for (int j0 = 0; j0 < 512; j0 += 64) {
        float acc[4][4] = {{0.f}};
        for (int k0 = 0; k0 < 512; k0 += 16) {
            float4 av = *(const float4*)(obs + (row0 + l_r) * 512 + k0 + l_k4);
            float4 bv = *(const float4*)(cb + (long long)(j0 + l_r) * 512 + k0 + l_k4);
            __syncthreads();    // previous compute phase done before overwrite
            As[l_k4 + 0][l_r] = av.x; As[l_k4 + 1][l_r] = av.y;
            As[l_k4 + 2][l_r] = av.z; As[l_k4 + 3][l_r] = av.w;
            Bs[l_k4 + 0][l_r] = bv.x; Bs[l_k4 + 1][l_r] = bv.y;
            Bs[l_k4 + 2][l_r] = bv.z; Bs[l_k4 + 3][l_r] = bv.w;
            __syncthreads();
            #pragma unroll
            for (int kk = 0; kk < 16; ++kk) {
                float ra[4], rb[4];
                #pragma unroll
                for (int i = 0; i < 4; ++i) ra[i] = As[kk][ty * 4 + i];
                #pragma unroll
                for (int j = 0; j < 4; ++j) rb[j] = Bs[kk][tx * 4 + j];
                #pragma unroll
                for (int i = 0; i < 4; ++i)
                    #pragma unroll
                    for (int j = 0; j < 4; ++j)
                        acc[i][j] = fmaf(ra[i], rb[j], acc[i][j]);
            }
        }
        __syncthreads();
        #pragma unroll
        for (int i = 0; i < 4; ++i) {
            int rr = ty * 4 + i;
            float bv = 3.4e38f; int bi = 0;
            #pragma unroll
            for (int j = 0; j < 4; ++j) {
                int jj = j0 + tx * 4 + j;
                float d2 = (n2o[rr] - 2.f * acc[i][j]) + n2cb[jj];
                if (d2 < bv) { bv = d2; bi = jj; }
            }
            rv[rr][tx] = bv; ri[rr][tx] = bi;
        }
        __syncthreads();
        if (tid < 64) {
            float bv = bestv[tid]; int bi = besti[tid];
            for (int t = 0; t < 16; ++t)
                if (rv[tid][t] < bv) { bv = rv[tid][t]; bi = ri[tid][t]; }
            bestv[tid] = bv; besti[tid] = bi;
        }
        __syncthreads();
    }
    if (tid < 64) codes[row0 + tid] = besti[tid];
}

// latent[r,:] = codebook[codes[r],:]
__global__ __launch_bounds__(128) void gather_latent(
    const float* __restrict__ cb, const int* __restrict__ codes,
    float* __restrict__ latent)
{
    long long r = blockIdx.x;
    int c = codes[r];
    const float4* src = (const float4*)(cb + (long long)c * 512);
    float4*       dst = (float4*)(latent + r * 512);
    dst[threadIdx.x] = src[threadIdx.x];
}

// hdec[b,h] = relu(db1[h] + sum_s T[s][codes[b*16+s]][h]),  T = (16,512,500)
__global__ __launch_bounds__(128) void dec1_gather(
    const float* __restrict__ T, const int* __restrict__ codes,
    const float* __restrict__ b1, float* __restrict__ hdec)
{
    __shared__ int cds[16];
    int b = blockIdx.y;
    int h = blockIdx.x * 128 + threadIdx.x;
    if (threadIdx.x < 16) cds[threadIdx.x] = codes[b * 16 + threadIdx.x];
    __syncthreads();
    if (h >= 500) return;
    float acc = b1[h];
    #pragma unroll
    for (int s = 0; s < 16; ++s)
        acc += T[((long long)s * 512 + cds[s]) * 500 + h];
    hdec[(long long)b * 500 + h] = fmaxf(acc, 0.f);
}

extern "C" void kernel_launch(void* const* d_in, const int* in_sizes, int n_in,
                              void* d_out, int out_size, void* d_ws, size_t ws_size,
                              hipStream_t stream)
{
    const float* x   = (const float*)d_in[0];
    const float* ew1 = (const float*)d_in[1];
    const float* eb1 = (const float*)d_in[2];
    const float* ew2 = (const float*)d_in[3];
    const float* eb2 = (const float*)d_in[4];
    const float* ew3 = (const float*)d_in[5];
    const float* eb3 = (const float*)d_in[6];
    const float* cb  = (const float*)d_in[7];
    const float* dw1 = (const float*)d_in[8];
    const float* db1 = (const float*)d_in[9];
    const float* dw2 = (const float*)d_in[10];
    const float* db2 = (const float*)d_in[11];

    const int B = 8192, D = 784, H = 500, C = 512, S = 16;
    const int R = B * S;       // 131072
    const int CS = C * S;      // 8192

    float* out    = (float*)d_out;
    float* recon  = out;                       // B*D
    float* obs    = recon + (long long)B * D;  // R*C
    float* latent = obs + (long long)R * C;    // R*C (also used as z)

    float* ws   = (float*)d_ws;
    float* h1   = ws;                           // B*H
    float* h2   = h1 + (long long)B * H;        // B*H
    float* hdec = h2 + (long long)B * H;        // B*H
    float* T    = hdec + (long long)B * H;      // S*C*H
    float* n2cb = T + (long long)S * C * H;     // C
    int* codes  = (int*)(n2cb + C);             // R

    dim3 blk(256);

    // encoder
    gemm_bias_act<<<dim3((H + 127) / 128, B / 128, 1), blk, 0, stream>>>(
        x, ew1, eb1, h1, B, H, D, 1, 0, 0, 0);
    gemm_bias_act<<<dim3((H + 127) / 128, B / 128, 1), blk, 0, stream>>>(
        h1, ew2, eb2, h2, B, H, H, 1, 0, 0, 0);
    gemm_bias_act<<<dim3(CS / 128, B / 128, 1), blk, 0, stream>>>(
        h2, ew3, eb3, obs, B, CS, H, 0, 0, 0, 0);

    // VQ
    row_norm2<<<C, 64, 0, stream>>>(cb, n2cb);
    vq_argmin<<<R / 64, 256, 0, stream>>>(obs, cb, n2cb, codes);
    gather_latent<<<R, 128, 0, stream>>>(cb, codes, latent);

    // decoder via T_s = codebook @ dec_w1[s*C:(s+1)*C, :]
    gemm_bias_act<<<dim3((H + 127) / 128, C / 128, S), blk, 0, stream>>>(
        cb, dw1, nullptr, T, C, H, C, 0,
        0, (long long)C * H, (long long)C * H);
    dec1_gather<<<dim3((H + 127) / 128, B, 1), dim3(128), 0, stream>>>(
        T, codes, db1, hdec);
    gemm_bias_act<<<dim3((D + 127) / 128, B / 128, 1), blk, 0, stream>>>(
        hdec, dw2, db2, recon, B, D, H, 0, 0, 0, 0);
}